// Round 15
// baseline (272.839 us; speedup 1.0000x reference)
//
#include <hip/hip_runtime.h>

#define NB 4
#define NS 2048
#define NE 1024
#define NH 16
#define ND 64
#define KVB 64

typedef unsigned short ushort_t;
typedef __attribute__((ext_vector_type(8))) short bf16x8;
typedef __attribute__((ext_vector_type(4))) float f32x4;

#define KQPRE 0.18033688011112042f   // 0.125 * log2(e), folded into q at gemm1

static __device__ __forceinline__ ushort_t f2bf(float f) {
    union { float f; unsigned int u; } v; v.f = f;
    unsigned int r = v.u + 0x7FFF + ((v.u >> 16) & 1);   // RNE
    return (ushort_t)(r >> 16);
}
static __device__ __forceinline__ float bf2f(ushort_t b) {
    union { unsigned u; float f; } v; v.u = ((unsigned)b) << 16;
    return v.f;
}

static __device__ __forceinline__ unsigned pk_bf16(float lo, float hi) {
    unsigned r;
    asm("v_cvt_pk_bf16_f32 %0, %1, %2" : "=v"(r) : "v"(lo), "v"(hi));
    return r;
}

static __device__ __forceinline__ void gload16(const void* g, void* l) {
    __builtin_amdgcn_global_load_lds(
        (const __attribute__((address_space(1))) void*)g,
        (__attribute__((address_space(3))) void*)l,
        16, 0, 0);
}

// ===========================================================================
// fused fp32 -> bf16 bulk convert for x (4096 blks), Win (1536), Wout (512)
// ===========================================================================
__global__ __launch_bounds__(256)
void cvt3_f32_bf16(const float* __restrict__ x,  ushort_t* __restrict__ xb,
                   const float* __restrict__ Wi, ushort_t* __restrict__ Wib,
                   const float* __restrict__ Wo, ushort_t* __restrict__ Wob)
{
    const int blk = blockIdx.x;
    const float* src; ushort_t* dst; int i;
    if (blk < 4096)      { src = x;  dst = xb;  i = blk * 256 + threadIdx.x; }
    else if (blk < 5632) { src = Wi; dst = Wib; i = (blk - 4096) * 256 + threadIdx.x; }
    else                 { src = Wo; dst = Wob; i = (blk - 5632) * 256 + threadIdx.x; }
    const float4 a = ((const float4*)src)[i * 2];
    const float4 b = ((const float4*)src)[i * 2 + 1];
    union { ushort_t us[8]; uint4 v; } pk;
    pk.us[0] = f2bf(a.x); pk.us[1] = f2bf(a.y); pk.us[2] = f2bf(a.z); pk.us[3] = f2bf(a.w);
    pk.us[4] = f2bf(b.x); pk.us[5] = f2bf(b.y); pk.us[6] = f2bf(b.z); pk.us[7] = f2bf(b.w);
    ((uint4*)dst)[i] = pk.v;
}

// ===========================================================================
// bf16 MFMA GEMM (m97 structure) — verified rounds 2-14, + T1 XCD swizzle.
// EPI=0: fp32 row-major C[M][N].
// EPI=1: q,k thirds -> qkvb[t][b][h][s][d] rows (q pre-scaled by 0.125*log2e);
//        v third: MFMA operands SWAPPED (same fragment semantics as attn's
//        QK^T swap; A/B layouts identical for 16x16x32) -> D^T in registers,
//        epilogue writes tile-blocked V^T: vt[b][h][kt][d][kv64]
//        (8KB contiguous per 64x64 tile; 32B-segment coalesced stores).
// ===========================================================================
template<int EPI>
__global__ __launch_bounds__(256)
void gemm_bf16(const ushort_t* __restrict__ A, const ushort_t* __restrict__ W,
               const float* __restrict__ bias, float* __restrict__ C,
               ushort_t* __restrict__ Cb, int M, int N, int K)
{
    __shared__ ushort_t As[128 * 32];
    __shared__ ushort_t Bs[128 * 32];
    const int tid  = threadIdx.x;
    const int lane = tid & 63;
    const int wid  = tid >> 6;
    const int lr   = lane & 15;
    const int lg   = lane >> 4;

    // T1: XCD-chunked bijective swizzle (nwg % 8 == 0 for both GEMMs)
    const int lin   = blockIdx.y * gridDim.x + blockIdx.x;
    const int chunk = (gridDim.x * gridDim.y) >> 3;
    const int lin2  = (lin & 7) * chunk + (lin >> 3);
    const int bx    = lin2 % gridDim.x;
    const int by    = lin2 / gridDim.x;
    const int m0 = by * 128;
    const int n0 = bx * 128;
    const int wr = wid >> 1, wc = wid & 1;

    const bool swapv = (EPI == 1) && (n0 >= 2 * NE);   // v third, block-uniform

    size_t srcoff[2];
    int ldsoff[2];
#pragma unroll
    for (int p = 0; p < 2; ++p) {
        const int chnk = p * 256 + tid;
        const int row = chnk >> 2;
        const int sp  = chnk & 3;
        const int c   = sp ^ ((row >> 1) & 3);
        srcoff[p] = (size_t)row * K + c * 8;
        ldsoff[p] = (p * 256 + wid * 64) * 8;
    }
    const ushort_t* Ag = A + (size_t)m0 * K;
    const ushort_t* Wg = W + (size_t)n0 * K;

    int offa[4], offb[4];
#pragma unroll
    for (int f = 0; f < 4; ++f) {
        const int ra = wr * 64 + f * 16 + lr;
        offa[f] = ra * 32 + (lg ^ ((ra >> 1) & 3)) * 8;
        const int rb = wc * 64 + f * 16 + lr;
        offb[f] = rb * 32 + (lg ^ ((rb >> 1) & 3)) * 8;
    }

    f32x4 acc[4][4];
#pragma unroll
    for (int i = 0; i < 4; ++i)
#pragma unroll
        for (int j = 0; j < 4; ++j) acc[i][j] = (f32x4){0.f, 0.f, 0.f, 0.f};

    for (int k0 = 0; k0 < K; k0 += 32) {
        __syncthreads();
#pragma unroll
        for (int p = 0; p < 2; ++p) {
            gload16(Ag + srcoff[p] + k0, (ushort_t*)As + ldsoff[p]);
            gload16(Wg + srcoff[p] + k0, (ushort_t*)Bs + ldsoff[p]);
        }
        __syncthreads();
        bf16x8 af[4], bfr[4];
#pragma unroll
        for (int f = 0; f < 4; ++f) {
            af[f]  = *(const bf16x8*)&As[offa[f]];
            bfr[f] = *(const bf16x8*)&Bs[offb[f]];
        }
        if (!swapv) {
#pragma unroll
            for (int mf = 0; mf < 4; ++mf)
#pragma unroll
                for (int nf = 0; nf < 4; ++nf)
                    acc[mf][nf] = __builtin_amdgcn_mfma_f32_16x16x32_bf16(
                        af[mf], bfr[nf], acc[mf][nf], 0, 0, 0);
        } else {
#pragma unroll
            for (int mf = 0; mf < 4; ++mf)
#pragma unroll
                for (int nf = 0; nf < 4; ++nf)
                    acc[mf][nf] = __builtin_amdgcn_mfma_f32_16x16x32_bf16(
                        bfr[nf], af[mf], acc[mf][nf], 0, 0, 0);
        }
    }

    if (EPI == 0) {
#pragma unroll
        for (int nf = 0; nf < 4; ++nf) {
            const int n = n0 + wc * 64 + nf * 16 + lr;
            const float bj = bias[n];
#pragma unroll
            for (int mf = 0; mf < 4; ++mf)
#pragma unroll
                for (int r = 0; r < 4; ++r) {
                    const int m = m0 + wr * 64 + mf * 16 + lg * 4 + r;
                    C[(size_t)m * N + n] = acc[mf][nf][r] + bj;
                }
        }
    } else if (!swapv) {
        // q,k thirds: row scatter (verified)
#pragma unroll
        for (int nf = 0; nf < 4; ++nf) {
            const int n = n0 + wc * 64 + nf * 16 + lr;
            const float bj = bias[n];
            const int t = n >> 10;
            const int h = (n >> 6) & (NH - 1);
            const int d = n & (ND - 1);
#pragma unroll
            for (int mf = 0; mf < 4; ++mf)
#pragma unroll
                for (int r = 0; r < 4; ++r) {
                    const int m = m0 + wr * 64 + mf * 16 + lg * 4 + r;
                    const int b = m >> 11;
                    const int s = m & (NS - 1);
                    float v = acc[mf][nf][r] + bj;
                    if (t == 0) v *= KQPRE;        // q pre-scale (fp32, pre-round)
                    Cb[((size_t)((t * NB + b) * NH + h) * NS + s) * ND + d] = f2bf(v);
                }
        }
    } else {
        // v third, transposed acc: value(m = m0+wr*64+mf*16+lr,
        //                               n = n0+wc*64+nf*16+lg*4+r)
        const int hv = ((n0 + wc * 64) >> 6) & (NH - 1);
        const size_t vtoff = (size_t)2 * NB * NH * NS * ND;
#pragma unroll
        for (int nf = 0; nf < 4; ++nf) {
            const float4 bv = *(const float4*)&bias[n0 + wc * 64 + nf * 16 + lg * 4];
            const float bj[4] = {bv.x, bv.y, bv.z, bv.w};
#pragma unroll
            for (int mf = 0; mf < 4; ++mf) {
                const int m = m0 + wr * 64 + mf * 16 + lr;
                const int b = m >> 11;
                const int s = m & (NS - 1);
                const size_t rowbase = vtoff
                    + (((size_t)(b * NH + hv)) * 32 + (s >> 6)) * 4096 + (s & 63);
#pragma unroll
                for (int r = 0; r < 4; ++r) {
                    const int d = nf * 16 + lg * 4 + r;
                    Cb[rowbase + (size_t)d * 64] = f2bf(acc[mf][nf][r] + bj[r]);
                }
            }
        }
    }
}

// ===========================================================================
// Swapped-operand bf16 MFMA flash attention — r14 (verified, 150.5 µs) with
// the V path simplified: V arrives tile-blocked V^T[b][h][kt][d][kv64] from
// gemm1, so staging is two b128 copies (form-identical to the verified K
// path) into Vs[64][70] (stride 70: write & read both ~2-way, free) and the
// scalar-transpose XOR-swizzle staging is DELETED. Read semantics identical:
// vf[j] = V[kv = kh*32+lg*8+j][d = dk*16+lr].
// RoPE fused (Q in registers once; K at T14-prefetch), ones-MFMA rowsum,
// exp2 softmax, T1/T5, B3-as-fence: all r13/r14-verified, unchanged.
// ===========================================================================
__global__ __launch_bounds__(256)
void attn_kernel(const ushort_t* __restrict__ qkvb, ushort_t* __restrict__ obuf,
                 const float* __restrict__ cosT, const float* __restrict__ sinT)
{
    __shared__ ushort_t Ks[64 * 72];
    __shared__ ushort_t Vs[64 * 70];
    __shared__ ushort_t Ps[128 * 72];

    const int tid  = threadIdx.x;
    const int lane = tid & 63;
    const int wid  = tid >> 6;
    const int lr   = lane & 15;
    const int lg   = lane >> 4;

    // bijective digit-swap: XCD x serves bh in [8x, 8x+8) (L2-resident K/V)
    const int orig = blockIdx.x;                 // 0..1023
    const int wg   = (orig & 7) * 128 + (orig >> 3);
    const int bh   = wg >> 4;
    const int b = bh >> 4, h = bh & (NH - 1);
    const int q0 = (wg & 15) * 128;

    const ushort_t* qbase = qkvb + ((size_t)((0 * NB + b) * NH + h)) * (NS * ND);
    const ushort_t* kbase = qkvb + ((size_t)((1 * NB + b) * NH + h)) * (NS * ND);
    const ushort_t* vbase = qkvb + (size_t)2 * NB * NH * NS * ND
                                 + ((size_t)(b * NH + h)) * 32 * 4096;  // [kt][d][kv]

    // ones B-fragment (bf16 1.0) for rowsum MFMA
    bf16x8 onesf;
#pragma unroll
    for (int j = 0; j < 8; ++j) onesf[j] = (short)0x3F80;

    // ---- Q fragments: load lo/hi halves, apply RoPE in f32, pack bf16 ----
    bf16x8 qf[2][2];
#pragma unroll
    for (int st = 0; st < 2; ++st) {
        const int sq = q0 + wid * 32 + st * 16 + lr;
        union { bf16x8 v; ushort_t us[8]; } qlo, qhi;
        qlo.v = *(const bf16x8*)(qbase + (size_t)sq * ND + lg * 8);
        qhi.v = *(const bf16x8*)(qbase + (size_t)sq * ND + 32 + lg * 8);
        const float4 c0 = *(const float4*)(cosT + sq * ND + lg * 8);
        const float4 c1 = *(const float4*)(cosT + sq * ND + lg * 8 + 4);
        const float4 s0 = *(const float4*)(sinT + sq * ND + lg * 8);
        const float4 s1 = *(const float4*)(sinT + sq * ND + lg * 8 + 4);
        const float cc[8] = {c0.x, c0.y, c0.z, c0.w, c1.x, c1.y, c1.z, c1.w};
        const float ss[8] = {s0.x, s0.y, s0.z, s0.w, s1.x, s1.y, s1.z, s1.w};
        union { bf16x8 v; ushort_t us[8]; } olo, ohi;
#pragma unroll
        for (int j = 0; j < 8; ++j) {
            const float x1 = bf2f(qlo.us[j]);
            const float x2 = bf2f(qhi.us[j]);
            olo.us[j] = f2bf(x1 * cc[j] - x2 * ss[j]);
            ohi.us[j] = f2bf(x2 * cc[j] + x1 * ss[j]);
        }
        qf[st][0] = olo.v;
        qf[st][1] = ohi.v;
    }

    // staging indices: thread covers rows {tid>>3, 32+(tid>>3)}, chunk tid&7
    const int sc = tid & 7;
    const int sr0 = tid >> 3;

    // K rope+pack state (roped bf16 pairs); V b128 prefetch regs
    uint2 klo[2], khi[2];
    uint4 vrg[2];
#pragma unroll
    for (int it = 0; it < 2; ++it) {
        const int r = sr0 + it * 32;                 // row (kt=0)
        const ushort_t* kr = kbase + (size_t)r * ND + sc * 4;
        union { uint2 v; ushort_t us[4]; } lo, hi;
        lo.v = *(const uint2*)kr;
        hi.v = *(const uint2*)(kr + 32);
        const float4 cv = *(const float4*)(cosT + r * ND + sc * 4);
        const float4 sv = *(const float4*)(sinT + r * ND + sc * 4);
        const float cc[4] = {cv.x, cv.y, cv.z, cv.w};
        const float ss[4] = {sv.x, sv.y, sv.z, sv.w};
        float ol[4], oh[4];
#pragma unroll
        for (int j = 0; j < 4; ++j) {
            const float x1 = bf2f(lo.us[j]);
            const float x2 = bf2f(hi.us[j]);
            ol[j] = x1 * cc[j] - x2 * ss[j];
            oh[j] = x2 * cc[j] + x1 * ss[j];
        }
        klo[it] = make_uint2(pk_bf16(ol[0], ol[1]), pk_bf16(ol[2], ol[3]));
        khi[it] = make_uint2(pk_bf16(oh[0], oh[1]), pk_bf16(oh[2], oh[3]));
        vrg[it] = *(const uint4*)(vbase + (size_t)r * 64 + sc * 8);  // V^T tile 0
    }

    f32x4 acc_o[2][4];
    f32x4 acc_l[2];
#pragma unroll
    for (int st = 0; st < 2; ++st) {
        acc_l[st] = (f32x4){0.f, 0.f, 0.f, 0.f};
#pragma unroll
        for (int dk = 0; dk < 4; ++dk) acc_o[st][dk] = (f32x4){0.f, 0.f, 0.f, 0.f};
    }

    for (int kt = 0; kt < NS; kt += KVB) {
        __syncthreads();                         // B1: prev tile reads done
        // ---- stage K (roped, two b64) and V^T (two b128, like K path) ----
#pragma unroll
        for (int it = 0; it < 2; ++it) {
            const int r = sr0 + it * 32;
            *(uint2*)&Ks[r * 72 + sc * 4]      = klo[it];
            *(uint2*)&Ks[r * 72 + sc * 4 + 32] = khi[it];
            *(uint4*)&Vs[r * 70 + sc * 8]      = vrg[it];
        }
        __syncthreads();                         // B2: staging visible
        // ---- T14: prefetch next tile; rope K in registers (overlapped) ----
        if (kt + KVB < NS) {
            const ushort_t* vtile = vbase + (size_t)((kt + KVB) >> 6) * 4096;
#pragma unroll
            for (int it = 0; it < 2; ++it) {
                const int r = kt + KVB + sr0 + it * 32;     // absolute kv row
                const ushort_t* kr = kbase + (size_t)r * ND + sc * 4;
                union { uint2 v; ushort_t us[4]; } lo, hi;
                lo.v = *(const uint2*)kr;
                hi.v = *(const uint2*)(kr + 32);
                const float4 cv = *(const float4*)(cosT + r * ND + sc * 4);
                const float4 sv = *(const float4*)(sinT + r * ND + sc * 4);
                const float cc[4] = {cv.x, cv.y, cv.z, cv.w};
                const float ss[4] = {sv.x, sv.y, sv.z, sv.w};
                float ol[4], oh[4];
#pragma unroll
                for (int j = 0; j < 4; ++j) {
                    const float x1 = bf2f(lo.us[j]);
                    const float x2 = bf2f(hi.us[j]);
                    ol[j] = x1 * cc[j] - x2 * ss[j];
                    oh[j] = x2 * cc[j] + x1 * ss[j];
                }
                klo[it] = make_uint2(pk_bf16(ol[0], ol[1]), pk_bf16(ol[2], ol[3]));
                khi[it] = make_uint2(pk_bf16(oh[0], oh[1]), pk_bf16(oh[2], oh[3]));
                vrg[it] = *(const uint4*)(vtile + (size_t)(sr0 + it * 32) * 64 + sc * 8);
            }
        }

        // ---- S^T = K Q^T ----
        f32x4 s[2][4];
#pragma unroll
        for (int st = 0; st < 2; ++st)
#pragma unroll
            for (int kvf = 0; kvf < 4; ++kvf) s[st][kvf] = (f32x4){0.f, 0.f, 0.f, 0.f};
        __builtin_amdgcn_s_setprio(1);
#pragma unroll
        for (int kh = 0; kh < 2; ++kh)
#pragma unroll
            for (int kvf = 0; kvf < 4; ++kvf) {
                const bf16x8 kf = *(const bf16x8*)&Ks[(kvf * 16 + lr) * 72 + kh * 32 + lg * 8];
                s[0][kvf] = __builtin_amdgcn_mfma_f32_16x16x32_bf16(kf, qf[0][kh], s[0][kvf], 0, 0, 0);
                s[1][kvf] = __builtin_amdgcn_mfma_f32_16x16x32_bf16(kf, qf[1][kh], s[1][kvf], 0, 0, 0);
            }
        __builtin_amdgcn_s_setprio(0);

        // ---- softmax: p = exp2(s) (scale pre-folded), packed P store ----
#pragma unroll
        for (int st = 0; st < 2; ++st) {
            const int prow = (wid * 32 + st * 16 + lr) * 72;
#pragma unroll
            for (int kvf = 0; kvf < 4; ++kvf) {
                const float p0 = __builtin_amdgcn_exp2f(s[st][kvf][0]);
                const float p1 = __builtin_amdgcn_exp2f(s[st][kvf][1]);
                const float p2 = __builtin_amdgcn_exp2f(s[st][kvf][2]);
                const float p3 = __builtin_amdgcn_exp2f(s[st][kvf][3]);
                const unsigned w01 = pk_bf16(p0, p1);
                const unsigned w23 = pk_bf16(p2, p3);
                *(uint2*)&Ps[prow + kvf * 16 + lg * 4] = make_uint2(w01, w23);
            }
        }
        // B3 relaxed: intra-wave P ordering fence (r10-r14 verified; rule #18)
        asm volatile("s_waitcnt lgkmcnt(0)" ::: "memory");
        __builtin_amdgcn_sched_barrier(0);

        // ---- O += P V ; rowsum via ones-MFMA ----
        __builtin_amdgcn_s_setprio(1);
#pragma unroll
        for (int kh = 0; kh < 2; ++kh) {
            const bf16x8 pf0 = *(const bf16x8*)&Ps[(wid * 32 + 0  + lr) * 72 + kh * 32 + lg * 8];
            const bf16x8 pf1 = *(const bf16x8*)&Ps[(wid * 32 + 16 + lr) * 72 + kh * 32 + lg * 8];
            acc_l[0] = __builtin_amdgcn_mfma_f32_16x16x32_bf16(pf0, onesf, acc_l[0], 0, 0, 0);
            acc_l[1] = __builtin_amdgcn_mfma_f32_16x16x32_bf16(pf1, onesf, acc_l[1], 0, 0, 0);
#pragma unroll
            for (int dk = 0; dk < 4; ++dk) {
                const bf16x8 vf = *(const bf16x8*)&Vs[(dk * 16 + lr) * 70 + kh * 32 + lg * 8];
                acc_o[0][dk] = __builtin_amdgcn_mfma_f32_16x16x32_bf16(pf0, vf, acc_o[0][dk], 0, 0, 0);
                acc_o[1][dk] = __builtin_amdgcn_mfma_f32_16x16x32_bf16(pf1, vf, acc_o[1][dk], 0, 0, 0);
            }
        }
        __builtin_amdgcn_s_setprio(0);
    }

    // ---- epilogue: rowsum already in matching register rows — divide ----
#pragma unroll
    for (int st = 0; st < 2; ++st) {
        float invq[4];
#pragma unroll
        for (int reg = 0; reg < 4; ++reg)
            invq[reg] = 1.0f / acc_l[st][reg];
#pragma unroll
        for (int dk = 0; dk < 4; ++dk)
#pragma unroll
            for (int reg = 0; reg < 4; ++reg) {
                const int q = q0 + wid * 32 + st * 16 + lg * 4 + reg;
                const int d = dk * 16 + lr;
                obuf[((size_t)(b * NS + q)) * NE + h * ND + d] =
                    f2bf(acc_o[st][dk][reg] * invq[reg]);
            }
    }
}

// ===========================================================================
extern "C" void kernel_launch(void* const* d_in, const int* in_sizes, int n_in,
                              void* d_out, int out_size, void* d_ws, size_t ws_size,
                              hipStream_t stream)
{
    const float* x    = (const float*)d_in[0];
    const float* Win  = (const float*)d_in[1];
    const float* bin  = (const float*)d_in[2];
    const float* Wout = (const float*)d_in[3];
    const float* bout = (const float*)d_in[4];
    const float* cosT = (const float*)d_in[5];
    const float* sinT = (const float*)d_in[6];
    float* out  = (float*)d_out;

    ushort_t* qkvb  = (ushort_t*)d_ws;             // q,k rows + blocked V^T (t=2)
    ushort_t* obufb = qkvb + (size_t)3 * NB * NH * NS * ND;
    ushort_t* xb    = obufb + (size_t)NB * NS * NE;
    ushort_t* Wib   = xb + (size_t)NB * NS * NE;
    ushort_t* Wob   = Wib + (size_t)3 * NE * NE;

    // fused conversions: 4096 + 1536 + 512 = 6144 blocks
    cvt3_f32_bf16<<<6144, 256, 0, stream>>>(x, xb, Win, Wib, Wout, Wob);

    // 1) QKV projection (+ q pre-scale; v emitted as blocked V^T), UN-roped
    gemm_bf16<1><<<dim3(3 * NE / 128, NB * NS / 128), 256, 0, stream>>>(
        xb, Wib, bin, nullptr, qkvb, NB * NS, 3 * NE, NE);
    // 2) attention with fused RoPE -> bf16 obuf [B][S][E]
    attn_kernel<<<dim3(NB * NH * (NS / 128)), 256, 0, stream>>>(
        qkvb, obufb, cosT, sinT);
    // 3) output projection (bf16 MFMA, fp32 out)
    gemm_bf16<0><<<dim3(NE / 128, NB * NS / 128), 256, 0, stream>>>(
        obufb, Wob, bout, out, nullptr, NB * NS, NE, NE);
}

// Round 16
// 231.597 us; speedup vs baseline: 1.1781x; 1.1781x over previous
//
#include <hip/hip_runtime.h>

#define NB 4
#define NS 2048
#define NE 1024
#define NH 16
#define ND 64
#define KVB 64

typedef unsigned short ushort_t;
typedef __attribute__((ext_vector_type(8))) short bf16x8;
typedef __attribute__((ext_vector_type(4))) float f32x4;

#define KQPRE 0.18033688011112042f   // 0.125 * log2(e), folded into q at gemm1

static __device__ __forceinline__ ushort_t f2bf(float f) {
    union { float f; unsigned int u; } v; v.f = f;
    unsigned int r = v.u + 0x7FFF + ((v.u >> 16) & 1);   // RNE
    return (ushort_t)(r >> 16);
}
static __device__ __forceinline__ float bf2f(ushort_t b) {
    union { unsigned u; float f; } v; v.u = ((unsigned)b) << 16;
    return v.f;
}

static __device__ __forceinline__ unsigned pk_bf16(float lo, float hi) {
    unsigned r;
    asm("v_cvt_pk_bf16_f32 %0, %1, %2" : "=v"(r) : "v"(lo), "v"(hi));
    return r;
}

static __device__ __forceinline__ void gload16(const void* g, void* l) {
    __builtin_amdgcn_global_load_lds(
        (const __attribute__((address_space(1))) void*)g,
        (__attribute__((address_space(3))) void*)l,
        16, 0, 0);
}

// ===========================================================================
// fused fp32 -> bf16 bulk convert for x (4096 blks), Win (1536), Wout (512)
// ===========================================================================
__global__ __launch_bounds__(256)
void cvt3_f32_bf16(const float* __restrict__ x,  ushort_t* __restrict__ xb,
                   const float* __restrict__ Wi, ushort_t* __restrict__ Wib,
                   const float* __restrict__ Wo, ushort_t* __restrict__ Wob)
{
    const int blk = blockIdx.x;
    const float* src; ushort_t* dst; int i;
    if (blk < 4096)      { src = x;  dst = xb;  i = blk * 256 + threadIdx.x; }
    else if (blk < 5632) { src = Wi; dst = Wib; i = (blk - 4096) * 256 + threadIdx.x; }
    else                 { src = Wo; dst = Wob; i = (blk - 5632) * 256 + threadIdx.x; }
    const float4 a = ((const float4*)src)[i * 2];
    const float4 b = ((const float4*)src)[i * 2 + 1];
    union { ushort_t us[8]; uint4 v; } pk;
    pk.us[0] = f2bf(a.x); pk.us[1] = f2bf(a.y); pk.us[2] = f2bf(a.z); pk.us[3] = f2bf(a.w);
    pk.us[4] = f2bf(b.x); pk.us[5] = f2bf(b.y); pk.us[6] = f2bf(b.z); pk.us[7] = f2bf(b.w);
    ((uint4*)dst)[i] = pk.v;
}

// ===========================================================================
// bf16 MFMA GEMM (m97 structure) — verified rounds 2-15, + T1 XCD swizzle.
// EPI=0: fp32 row-major C[M][N].
// EPI=1: bf16 scatter to qkvb[t][b][h][s][d] with FUSED RoPE on q,k:
//        partner (d, d+32) = (nf, nf+2) in the SAME thread; rope in fp32
//        post-bias pre-round; q additionally scaled by 0.125*log2(e) ONCE
//        (r6's failure was a double-scale — rope math itself was correct).
// ===========================================================================
template<int EPI>
__global__ __launch_bounds__(256)
void gemm_bf16(const ushort_t* __restrict__ A, const ushort_t* __restrict__ W,
               const float* __restrict__ bias, float* __restrict__ C,
               ushort_t* __restrict__ Cb, const float* __restrict__ cosT,
               const float* __restrict__ sinT, int M, int N, int K)
{
    __shared__ ushort_t As[128 * 32];
    __shared__ ushort_t Bs[128 * 32];
    const int tid  = threadIdx.x;
    const int lane = tid & 63;
    const int wid  = tid >> 6;
    const int lr   = lane & 15;
    const int lg   = lane >> 4;

    // T1: XCD-chunked bijective swizzle (nwg % 8 == 0 for both GEMMs)
    const int lin   = blockIdx.y * gridDim.x + blockIdx.x;
    const int chunk = (gridDim.x * gridDim.y) >> 3;
    const int lin2  = (lin & 7) * chunk + (lin >> 3);
    const int bx    = lin2 % gridDim.x;
    const int by    = lin2 / gridDim.x;
    const int m0 = by * 128;
    const int n0 = bx * 128;
    const int wr = wid >> 1, wc = wid & 1;

    size_t srcoff[2];
    int ldsoff[2];
#pragma unroll
    for (int p = 0; p < 2; ++p) {
        const int chnk = p * 256 + tid;
        const int row = chnk >> 2;
        const int sp  = chnk & 3;
        const int c   = sp ^ ((row >> 1) & 3);
        srcoff[p] = (size_t)row * K + c * 8;
        ldsoff[p] = (p * 256 + wid * 64) * 8;
    }
    const ushort_t* Ag = A + (size_t)m0 * K;
    const ushort_t* Wg = W + (size_t)n0 * K;

    int offa[4], offb[4];
#pragma unroll
    for (int f = 0; f < 4; ++f) {
        const int ra = wr * 64 + f * 16 + lr;
        offa[f] = ra * 32 + (lg ^ ((ra >> 1) & 3)) * 8;
        const int rb = wc * 64 + f * 16 + lr;
        offb[f] = rb * 32 + (lg ^ ((rb >> 1) & 3)) * 8;
    }

    f32x4 acc[4][4];
#pragma unroll
    for (int i = 0; i < 4; ++i)
#pragma unroll
        for (int j = 0; j < 4; ++j) acc[i][j] = (f32x4){0.f, 0.f, 0.f, 0.f};

    for (int k0 = 0; k0 < K; k0 += 32) {
        __syncthreads();
#pragma unroll
        for (int p = 0; p < 2; ++p) {
            gload16(Ag + srcoff[p] + k0, (ushort_t*)As + ldsoff[p]);
            gload16(Wg + srcoff[p] + k0, (ushort_t*)Bs + ldsoff[p]);
        }
        __syncthreads();
        bf16x8 af[4], bfr[4];
#pragma unroll
        for (int f = 0; f < 4; ++f) {
            af[f]  = *(const bf16x8*)&As[offa[f]];
            bfr[f] = *(const bf16x8*)&Bs[offb[f]];
        }
#pragma unroll
        for (int mf = 0; mf < 4; ++mf)
#pragma unroll
            for (int nf = 0; nf < 4; ++nf)
                acc[mf][nf] = __builtin_amdgcn_mfma_f32_16x16x32_bf16(
                    af[mf], bfr[nf], acc[mf][nf], 0, 0, 0);
    }

    if (EPI == 0) {
#pragma unroll
        for (int nf = 0; nf < 4; ++nf) {
            const int n = n0 + wc * 64 + nf * 16 + lr;
            const float bj = bias[n];
#pragma unroll
            for (int mf = 0; mf < 4; ++mf)
#pragma unroll
                for (int r = 0; r < 4; ++r) {
                    const int m = m0 + wr * 64 + mf * 16 + lg * 4 + r;
                    C[(size_t)m * N + n] = acc[mf][nf][r] + bj;
                }
        }
    } else {
        const int tt = n0 >> 10;                 // 0=q 1=k 2=v, block-uniform
        float bj[4]; int hh[4];
#pragma unroll
        for (int nf = 0; nf < 4; ++nf) {
            const int n = n0 + wc * 64 + nf * 16 + lr;
            bj[nf] = bias[n];
            hh[nf] = (n >> 6) & (NH - 1);
        }
        // thread's 4 columns: d = nf*16 + lr  (nf,nf+2 are rope partners)
#pragma unroll
        for (int mf = 0; mf < 4; ++mf)
#pragma unroll
            for (int r = 0; r < 4; ++r) {
                const int m = m0 + wr * 64 + mf * 16 + lg * 4 + r;
                const int b = m >> 11;
                const int s = m & (NS - 1);
                float v[4];
#pragma unroll
                for (int nf = 0; nf < 4; ++nf) v[nf] = acc[mf][nf][r] + bj[nf];
                if (tt < 2) {                    // RoPE on q,k (fp32, pre-round)
#pragma unroll
                    for (int p = 0; p < 2; ++p) {
                        const int d = p * 16 + lr;          // < 32
                        const float c  = cosT[s * ND + d];  // table: c[d]==c[d+32]
                        const float sn = sinT[s * ND + d];
                        const float lo = v[p] * c - v[p + 2] * sn;
                        const float hi = v[p + 2] * c + v[p] * sn;
                        v[p] = lo; v[p + 2] = hi;
                    }
                    if (tt == 0) {               // q *= 0.125*log2e — ONCE
#pragma unroll
                        for (int nf = 0; nf < 4; ++nf) v[nf] *= KQPRE;
                    }
                }
#pragma unroll
                for (int nf = 0; nf < 4; ++nf)
                    Cb[((size_t)((tt * NB + b) * NH + hh[nf]) * NS + s) * ND
                       + nf * 16 + lr] = f2bf(v[nf]);
            }
    }
}

// ===========================================================================
// Swapped-operand bf16 MFMA flash attention — r13 VERBATIM (verified,
// 142.5 µs): no rope inside (q,k arrive roped; q pre-scaled so p=exp2(s)),
// ones-MFMA rowsum, packed P stores, B3-as-fence, T1/T5, T14 prefetch.
// ===========================================================================
__global__ __launch_bounds__(256)
void attn_kernel(const ushort_t* __restrict__ qkvb, ushort_t* __restrict__ obuf)
{
    __shared__ ushort_t Ks[64 * 72];
    __shared__ ushort_t Vs[64 * 64];
    __shared__ ushort_t Ps[128 * 72];

    const int tid  = threadIdx.x;
    const int lane = tid & 63;
    const int wid  = tid >> 6;
    const int lr   = lane & 15;
    const int lg   = lane >> 4;

    // bijective digit-swap: XCD x serves bh in [8x, 8x+8) (L2-resident K/V)
    const int orig = blockIdx.x;                 // 0..1023
    const int wg   = (orig & 7) * 128 + (orig >> 3);
    const int bh   = wg >> 4;
    const int b = bh >> 4, h = bh & (NH - 1);
    const int q0 = (wg & 15) * 128;

    const ushort_t* qbase = qkvb + ((size_t)((0 * NB + b) * NH + h)) * (NS * ND);
    const ushort_t* kbase = qkvb + ((size_t)((1 * NB + b) * NH + h)) * (NS * ND);
    const ushort_t* vbase = qkvb + ((size_t)((2 * NB + b) * NH + h)) * (NS * ND);

    // ones B-fragment (bf16 1.0) for rowsum MFMA
    bf16x8 onesf;
#pragma unroll
    for (int j = 0; j < 8; ++j) onesf[j] = (short)0x3F80;

    // Q fragments in registers (B operand): qf[strip][k-half]
    bf16x8 qf[2][2];
#pragma unroll
    for (int st = 0; st < 2; ++st)
#pragma unroll
        for (int kh = 0; kh < 2; ++kh)
            qf[st][kh] = *(const bf16x8*)(qbase + (size_t)(q0 + wid * 32 + st * 16 + lr) * ND
                                          + kh * 32 + lg * 8);

    // staging indices: thread covers rows {tid>>3, 32+(tid>>3)}, chunk tid&7
    const int sc = tid & 7;
    const int sr0 = tid >> 3;

    uint4 krg[2], vrg[2];
#pragma unroll
    for (int it = 0; it < 2; ++it) {
        const int r = sr0 + it * 32;
        krg[it] = *(const uint4*)(kbase + r * ND + sc * 8);
        vrg[it] = *(const uint4*)(vbase + r * ND + sc * 8);
    }

    f32x4 acc_o[2][4];
    f32x4 acc_l[2];
#pragma unroll
    for (int st = 0; st < 2; ++st) {
        acc_l[st] = (f32x4){0.f, 0.f, 0.f, 0.f};
#pragma unroll
        for (int dk = 0; dk < 4; ++dk) acc_o[st][dk] = (f32x4){0.f, 0.f, 0.f, 0.f};
    }

    for (int kt = 0; kt < NS; kt += KVB) {
        __syncthreads();                         // B1: prev tile reads done
        // ---- stage K (row-major pad 72) and V (d-major, XOR swizzle) ----
#pragma unroll
        for (int it = 0; it < 2; ++it) {
            const int r = sr0 + it * 32;
            *(uint4*)&Ks[r * 72 + sc * 8] = krg[it];
            union { uint4 v; ushort_t us[8]; } pu;
            pu.v = vrg[it];
#pragma unroll
            for (int j = 0; j < 8; ++j) {
                const int sw = (j ^ sc) << 4;
                Vs[(sc * 8 + j) * 64 + ((((r * 2) ^ sw)) >> 1)] = pu.us[j];
            }
        }
        __syncthreads();                         // B2: staging visible
        // ---- T14: issue next tile's global loads (hide under compute) ----
        if (kt + KVB < NS) {
#pragma unroll
            for (int it = 0; it < 2; ++it) {
                const int r = kt + KVB + sr0 + it * 32;
                krg[it] = *(const uint4*)(kbase + (size_t)r * ND + sc * 8);
                vrg[it] = *(const uint4*)(vbase + (size_t)r * ND + sc * 8);
            }
        }

        // ---- S^T = K Q^T ----
        f32x4 s[2][4];
#pragma unroll
        for (int st = 0; st < 2; ++st)
#pragma unroll
            for (int kvf = 0; kvf < 4; ++kvf) s[st][kvf] = (f32x4){0.f, 0.f, 0.f, 0.f};
        __builtin_amdgcn_s_setprio(1);
#pragma unroll
        for (int kh = 0; kh < 2; ++kh)
#pragma unroll
            for (int kvf = 0; kvf < 4; ++kvf) {
                const bf16x8 kf = *(const bf16x8*)&Ks[(kvf * 16 + lr) * 72 + kh * 32 + lg * 8];
                s[0][kvf] = __builtin_amdgcn_mfma_f32_16x16x32_bf16(kf, qf[0][kh], s[0][kvf], 0, 0, 0);
                s[1][kvf] = __builtin_amdgcn_mfma_f32_16x16x32_bf16(kf, qf[1][kh], s[1][kvf], 0, 0, 0);
            }
        __builtin_amdgcn_s_setprio(0);

        // ---- softmax: p = exp2(s) (scale pre-folded), packed P store ----
#pragma unroll
        for (int st = 0; st < 2; ++st) {
            const int prow = (wid * 32 + st * 16 + lr) * 72;
#pragma unroll
            for (int kvf = 0; kvf < 4; ++kvf) {
                const float p0 = __builtin_amdgcn_exp2f(s[st][kvf][0]);
                const float p1 = __builtin_amdgcn_exp2f(s[st][kvf][1]);
                const float p2 = __builtin_amdgcn_exp2f(s[st][kvf][2]);
                const float p3 = __builtin_amdgcn_exp2f(s[st][kvf][3]);
                const unsigned w01 = pk_bf16(p0, p1);
                const unsigned w23 = pk_bf16(p2, p3);
                *(uint2*)&Ps[prow + kvf * 16 + lg * 4] = make_uint2(w01, w23);
            }
        }
        // B3 relaxed: intra-wave P ordering fence (r10-r14 verified; rule #18)
        asm volatile("s_waitcnt lgkmcnt(0)" ::: "memory");
        __builtin_amdgcn_sched_barrier(0);

        // ---- O += P V ; rowsum via ones-MFMA ----
        __builtin_amdgcn_s_setprio(1);
#pragma unroll
        for (int kh = 0; kh < 2; ++kh) {
            const bf16x8 pf0 = *(const bf16x8*)&Ps[(wid * 32 + 0  + lr) * 72 + kh * 32 + lg * 8];
            const bf16x8 pf1 = *(const bf16x8*)&Ps[(wid * 32 + 16 + lr) * 72 + kh * 32 + lg * 8];
            acc_l[0] = __builtin_amdgcn_mfma_f32_16x16x32_bf16(pf0, onesf, acc_l[0], 0, 0, 0);
            acc_l[1] = __builtin_amdgcn_mfma_f32_16x16x32_bf16(pf1, onesf, acc_l[1], 0, 0, 0);
#pragma unroll
            for (int dk = 0; dk < 4; ++dk) {
                const int d = dk * 16 + lr;
                const int sw = ((d & 7) ^ ((d >> 3) & 7)) << 4;
                const bf16x8 vf = *(const bf16x8*)&Vs[d * 64 + (((kh * 64 + lg * 16) ^ sw) >> 1)];
                acc_o[0][dk] = __builtin_amdgcn_mfma_f32_16x16x32_bf16(pf0, vf, acc_o[0][dk], 0, 0, 0);
                acc_o[1][dk] = __builtin_amdgcn_mfma_f32_16x16x32_bf16(pf1, vf, acc_o[1][dk], 0, 0, 0);
            }
        }
        __builtin_amdgcn_s_setprio(0);
    }

    // ---- epilogue: rowsum already in matching register rows — divide ----
#pragma unroll
    for (int st = 0; st < 2; ++st) {
        float invq[4];
#pragma unroll
        for (int reg = 0; reg < 4; ++reg)
            invq[reg] = 1.0f / acc_l[st][reg];
#pragma unroll
        for (int dk = 0; dk < 4; ++dk)
#pragma unroll
            for (int reg = 0; reg < 4; ++reg) {
                const int q = q0 + wid * 32 + st * 16 + lg * 4 + reg;
                const int d = dk * 16 + lr;
                obuf[((size_t)(b * NS + q)) * NE + h * ND + d] =
                    f2bf(acc_o[st][dk][reg] * invq[reg]);
            }
    }
}

// ===========================================================================
extern "C" void kernel_launch(void* const* d_in, const int* in_sizes, int n_in,
                              void* d_out, int out_size, void* d_ws, size_t ws_size,
                              hipStream_t stream)
{
    const float* x    = (const float*)d_in[0];
    const float* Win  = (const float*)d_in[1];
    const float* bin  = (const float*)d_in[2];
    const float* Wout = (const float*)d_in[3];
    const float* bout = (const float*)d_in[4];
    const float* cosT = (const float*)d_in[5];
    const float* sinT = (const float*)d_in[6];
    float* out  = (float*)d_out;

    ushort_t* qkvb  = (ushort_t*)d_ws;
    ushort_t* obufb = qkvb + (size_t)3 * NB * NH * NS * ND;
    ushort_t* xb    = obufb + (size_t)NB * NS * NE;
    ushort_t* Wib   = xb + (size_t)NB * NS * NE;
    ushort_t* Wob   = Wib + (size_t)3 * NE * NE;

    // fused conversions: 4096 + 1536 + 512 = 6144 blocks
    cvt3_f32_bf16<<<6144, 256, 0, stream>>>(x, xb, Win, Wib, Wout, Wob);

    // 1) QKV projection with FUSED RoPE + q pre-scale -> bf16 qkv
    gemm_bf16<1><<<dim3(3 * NE / 128, NB * NS / 128), 256, 0, stream>>>(
        xb, Wib, bin, nullptr, qkvb, cosT, sinT, NB * NS, 3 * NE, NE);
    // 2) attention (r13-verbatim) -> bf16 obuf [B][S][E]
    attn_kernel<<<dim3(NB * NH * (NS / 128)), 256, 0, stream>>>(qkvb, obufb);
    // 3) output projection (bf16 MFMA, fp32 out)
    gemm_bf16<0><<<dim3(NE / 128, NB * NS / 128), 256, 0, stream>>>(
        obufb, Wob, bout, out, nullptr, nullptr, nullptr, NB * NS, NE, NE);
}

// Round 17
// 231.381 us; speedup vs baseline: 1.1792x; 1.0009x over previous
//
#include <hip/hip_runtime.h>

#define NB 4
#define NS 2048
#define NE 1024
#define NH 16
#define ND 64
#define KVB 64

typedef unsigned short ushort_t;
typedef __attribute__((ext_vector_type(8))) short bf16x8;
typedef __attribute__((ext_vector_type(4))) float f32x4;

#define KQPRE 0.18033688011112042f   // 0.125 * log2(e), folded into q at gemm1

static __device__ __forceinline__ ushort_t f2bf(float f) {
    union { float f; unsigned int u; } v; v.f = f;
    unsigned int r = v.u + 0x7FFF + ((v.u >> 16) & 1);   // RNE
    return (ushort_t)(r >> 16);
}
static __device__ __forceinline__ float bf2f(ushort_t b) {
    union { unsigned u; float f; } v; v.u = ((unsigned)b) << 16;
    return v.f;
}

static __device__ __forceinline__ unsigned pk_bf16(float lo, float hi) {
    unsigned r;
    asm("v_cvt_pk_bf16_f32 %0, %1, %2" : "=v"(r) : "v"(lo), "v"(hi));
    return r;
}

static __device__ __forceinline__ void gload16(const void* g, void* l) {
    __builtin_amdgcn_global_load_lds(
        (const __attribute__((address_space(1))) void*)g,
        (__attribute__((address_space(3))) void*)l,
        16, 0, 0);
}

// ===========================================================================
// fused fp32 -> bf16 bulk convert for x (4096 blks), Win (1536), Wout (512)
// ===========================================================================
__global__ __launch_bounds__(256)
void cvt3_f32_bf16(const float* __restrict__ x,  ushort_t* __restrict__ xb,
                   const float* __restrict__ Wi, ushort_t* __restrict__ Wib,
                   const float* __restrict__ Wo, ushort_t* __restrict__ Wob)
{
    const int blk = blockIdx.x;
    const float* src; ushort_t* dst; int i;
    if (blk < 4096)      { src = x;  dst = xb;  i = blk * 256 + threadIdx.x; }
    else if (blk < 5632) { src = Wi; dst = Wib; i = (blk - 4096) * 256 + threadIdx.x; }
    else                 { src = Wo; dst = Wob; i = (blk - 5632) * 256 + threadIdx.x; }
    const float4 a = ((const float4*)src)[i * 2];
    const float4 b = ((const float4*)src)[i * 2 + 1];
    union { ushort_t us[8]; uint4 v; } pk;
    pk.us[0] = f2bf(a.x); pk.us[1] = f2bf(a.y); pk.us[2] = f2bf(a.z); pk.us[3] = f2bf(a.w);
    pk.us[4] = f2bf(b.x); pk.us[5] = f2bf(b.y); pk.us[6] = f2bf(b.z); pk.us[7] = f2bf(b.w);
    ((uint4*)dst)[i] = pk.v;
}

// ===========================================================================
// gemm1_256: 256x256x(BK=64) bf16 MFMA GEMM with counted-vmcnt pipeline
// (T3+T4: raw s_barrier, prefetch stays in flight across barriers) and
// FUSED RoPE + q pre-scale epilogue (r16-verified math, re-indexed).
// A[M][K] @ W[N][K]^T + bias -> qkvb[t][b][h][s][d].  M=8192 N=3072 K=1024.
// 8 waves (2M x 4N), per-wave 128x64 output. LDS 128KB double-buffered.
// Swizzle: chunk c_phys = c_log ^ (row&7), applied on BOTH source (gload)
// and ds_read sides (rule #21); fragment reads land 2-way (free).
// ===========================================================================
__global__ __launch_bounds__(512, 2)
void gemm1_256(const ushort_t* __restrict__ A, const ushort_t* __restrict__ W,
               const float* __restrict__ bias, ushort_t* __restrict__ Cb,
               const float* __restrict__ cosT, const float* __restrict__ sinT)
{
    const int M = NB * NS, N = 3 * NE, K = NE;
    const int NK = K / 64;                    // 16 K-tiles
    __shared__ ushort_t As[2][256 * 64];
    __shared__ ushort_t Bs[2][256 * 64];

    const int tid  = threadIdx.x;
    const int lane = tid & 63;
    const int wid  = tid >> 6;                // 0..7
    const int lr   = lane & 15;
    const int lg   = lane >> 4;
    const int wr   = wid >> 2;                // 0..1 (M half)
    const int wc   = wid & 3;                 // 0..3 (N quarter)

    // T1 swizzle over 384 blocks (48 per XCD)
    const int orig = blockIdx.x;
    const int wg   = (orig & 7) * 48 + (orig >> 3);
    const int bx   = wg % 12;
    const int by   = wg / 12;
    const int m0 = by * 256, n0 = bx * 256;
    (void)M;

    // staging: chunk g = p*512 + tid; row = g>>3, c_phys = g&7
    size_t srcA[4], srcB[4];
    int dstoff[4];
#pragma unroll
    for (int p = 0; p < 4; ++p) {
        const int g   = p * 512 + tid;
        const int row = g >> 3;
        const int cl  = (g & 7) ^ (row & 7);
        srcA[p] = (size_t)(m0 + row) * K + cl * 8;
        srcB[p] = (size_t)(n0 + row) * K + cl * 8;
        dstoff[p] = (p * 512 + wid * 64) * 8;       // wave-uniform base (ushorts)
    }

    // fragment read offsets: row part + per-ksub swizzled chunk
    const int x7  = lr & 7;
    const int pc0 = ((0 + lg) ^ x7) * 8;            // ksub 0 chunk
    const int pc1 = ((4 + lg) ^ x7) * 8;            // ksub 1 chunk
    int offa[8], offb[4];
#pragma unroll
    for (int mf = 0; mf < 8; ++mf) offa[mf] = (wr * 128 + mf * 16 + lr) * 64;
#pragma unroll
    for (int nf = 0; nf < 4; ++nf) offb[nf] = (wc * 64 + nf * 16 + lr) * 64;

    f32x4 acc[8][4];
#pragma unroll
    for (int i = 0; i < 8; ++i)
#pragma unroll
        for (int j = 0; j < 4; ++j) acc[i][j] = (f32x4){0.f, 0.f, 0.f, 0.f};

    // prologue: stage tiles 0 and 1 (8 + 8 loads per thread)
#pragma unroll
    for (int p = 0; p < 4; ++p) {
        gload16(A + srcA[p], (ushort_t*)As[0] + dstoff[p]);
        gload16(W + srcB[p], (ushort_t*)Bs[0] + dstoff[p]);
    }
#pragma unroll
    for (int p = 0; p < 4; ++p) {
        gload16(A + srcA[p] + 64, (ushort_t*)As[1] + dstoff[p]);
        gload16(W + srcB[p] + 64, (ushort_t*)Bs[1] + dstoff[p]);
    }
    asm volatile("s_waitcnt vmcnt(8)" ::: "memory");   // tile 0 landed (mine)
    __builtin_amdgcn_s_barrier();                      // everyone's tile 0
    __builtin_amdgcn_sched_barrier(0);

    int cur = 0;
    for (int t = 0; t < NK; ++t) {
        bf16x8 af[8], bfv[4];
        // ---- ksub0: reads + MFMA ----
#pragma unroll
        for (int mf = 0; mf < 8; ++mf) af[mf] = *(const bf16x8*)&As[cur][offa[mf] + pc0];
#pragma unroll
        for (int nf = 0; nf < 4; ++nf) bfv[nf] = *(const bf16x8*)&Bs[cur][offb[nf] + pc0];
        __builtin_amdgcn_s_setprio(1);
#pragma unroll
        for (int mf = 0; mf < 8; ++mf)
#pragma unroll
            for (int nf = 0; nf < 4; ++nf)
                acc[mf][nf] = __builtin_amdgcn_mfma_f32_16x16x32_bf16(
                    af[mf], bfv[nf], acc[mf][nf], 0, 0, 0);
        __builtin_amdgcn_s_setprio(0);
        // ---- ksub1 reads ----
#pragma unroll
        for (int mf = 0; mf < 8; ++mf) af[mf] = *(const bf16x8*)&As[cur][offa[mf] + pc1];
#pragma unroll
        for (int nf = 0; nf < 4; ++nf) bfv[nf] = *(const bf16x8*)&Bs[cur][offb[nf] + pc1];
        asm volatile("s_waitcnt lgkmcnt(0)" ::: "memory");   // my reads done
        __builtin_amdgcn_sched_barrier(0);
        __builtin_amdgcn_s_barrier();                        // all reads of buf[cur] done
        __builtin_amdgcn_sched_barrier(0);
        // ---- overwrite buf[cur] with tile t+2 (stays in flight) ----
        if (t + 2 < NK) {
            const int koff = (t + 2) * 64;
#pragma unroll
            for (int p = 0; p < 4; ++p) {
                gload16(A + srcA[p] + koff, (ushort_t*)As[cur] + dstoff[p]);
                gload16(W + srcB[p] + koff, (ushort_t*)Bs[cur] + dstoff[p]);
            }
        }
        // ---- ksub1 MFMA (registers; overlaps the loads) ----
        __builtin_amdgcn_s_setprio(1);
#pragma unroll
        for (int mf = 0; mf < 8; ++mf)
#pragma unroll
            for (int nf = 0; nf < 4; ++nf)
                acc[mf][nf] = __builtin_amdgcn_mfma_f32_16x16x32_bf16(
                    af[mf], bfv[nf], acc[mf][nf], 0, 0, 0);
        __builtin_amdgcn_s_setprio(0);
        // ---- counted wait: tile t+1 landed; t+2 still in flight ----
        if (t + 1 < NK) {
            if (t + 2 < NK) asm volatile("s_waitcnt vmcnt(8)" ::: "memory");
            else            asm volatile("s_waitcnt vmcnt(0)" ::: "memory");
            __builtin_amdgcn_s_barrier();
            __builtin_amdgcn_sched_barrier(0);
        }
        cur ^= 1;
    }

    // ---- epilogue: bias + fused RoPE + q pre-scale + bf16 scatter ----
    const int tt = n0 >> 10;                  // 0=q 1=k 2=v (uniform: 256|1024)
    const int nbase = n0 + wc * 64;           // wave's 64-col slice = one head
    const int h = (nbase >> 6) & (NH - 1);
    float bj[4];
#pragma unroll
    for (int nf = 0; nf < 4; ++nf) bj[nf] = bias[nbase + nf * 16 + lr];
#pragma unroll
    for (int mf = 0; mf < 8; ++mf)
#pragma unroll
        for (int r = 0; r < 4; ++r) {
            const int m = m0 + wr * 128 + mf * 16 + lg * 4 + r;
            const int b = m >> 11;
            const int s = m & (NS - 1);
            float v[4];
#pragma unroll
            for (int nf = 0; nf < 4; ++nf) v[nf] = acc[mf][nf][r] + bj[nf];
            if (tt < 2) {                     // RoPE on q,k (fp32, pre-round)
#pragma unroll
                for (int p = 0; p < 2; ++p) {
                    const int d = p * 16 + lr;           // < 32
                    const float c  = cosT[s * ND + d];   // table halves duplicated
                    const float sn = sinT[s * ND + d];
                    const float lo = v[p] * c - v[p + 2] * sn;
                    const float hi = v[p + 2] * c + v[p] * sn;
                    v[p] = lo; v[p + 2] = hi;
                }
                if (tt == 0) {                // q *= 0.125*log2e — once
#pragma unroll
                    for (int nf = 0; nf < 4; ++nf) v[nf] *= KQPRE;
                }
            }
#pragma unroll
            for (int nf = 0; nf < 4; ++nf)
                Cb[((size_t)((tt * NB + b) * NH + h) * NS + s) * ND
                   + nf * 16 + lr] = f2bf(v[nf]);
        }
}

// ===========================================================================
// bf16 MFMA GEMM (m97 structure) — r16-verbatim; used for gemm2 (EPI=0).
// ===========================================================================
template<int EPI>
__global__ __launch_bounds__(256)
void gemm_bf16(const ushort_t* __restrict__ A, const ushort_t* __restrict__ W,
               const float* __restrict__ bias, float* __restrict__ C,
               ushort_t* __restrict__ Cb, const float* __restrict__ cosT,
               const float* __restrict__ sinT, int M, int N, int K)
{
    __shared__ ushort_t As[128 * 32];
    __shared__ ushort_t Bs[128 * 32];
    const int tid  = threadIdx.x;
    const int lane = tid & 63;
    const int wid  = tid >> 6;
    const int lr   = lane & 15;
    const int lg   = lane >> 4;

    const int lin   = blockIdx.y * gridDim.x + blockIdx.x;
    const int chunk = (gridDim.x * gridDim.y) >> 3;
    const int lin2  = (lin & 7) * chunk + (lin >> 3);
    const int bx    = lin2 % gridDim.x;
    const int by    = lin2 / gridDim.x;
    const int m0 = by * 128;
    const int n0 = bx * 128;
    const int wr = wid >> 1, wc = wid & 1;

    size_t srcoff[2];
    int ldsoff[2];
#pragma unroll
    for (int p = 0; p < 2; ++p) {
        const int chnk = p * 256 + tid;
        const int row = chnk >> 2;
        const int sp  = chnk & 3;
        const int c   = sp ^ ((row >> 1) & 3);
        srcoff[p] = (size_t)row * K + c * 8;
        ldsoff[p] = (p * 256 + wid * 64) * 8;
    }
    const ushort_t* Ag = A + (size_t)m0 * K;
    const ushort_t* Wg = W + (size_t)n0 * K;

    int offa[4], offb[4];
#pragma unroll
    for (int f = 0; f < 4; ++f) {
        const int ra = wr * 64 + f * 16 + lr;
        offa[f] = ra * 32 + (lg ^ ((ra >> 1) & 3)) * 8;
        const int rb = wc * 64 + f * 16 + lr;
        offb[f] = rb * 32 + (lg ^ ((rb >> 1) & 3)) * 8;
    }

    f32x4 acc[4][4];
#pragma unroll
    for (int i = 0; i < 4; ++i)
#pragma unroll
        for (int j = 0; j < 4; ++j) acc[i][j] = (f32x4){0.f, 0.f, 0.f, 0.f};

    for (int k0 = 0; k0 < K; k0 += 32) {
        __syncthreads();
#pragma unroll
        for (int p = 0; p < 2; ++p) {
            gload16(Ag + srcoff[p] + k0, (ushort_t*)As + ldsoff[p]);
            gload16(Wg + srcoff[p] + k0, (ushort_t*)Bs + ldsoff[p]);
        }
        __syncthreads();
        bf16x8 af[4], bfr[4];
#pragma unroll
        for (int f = 0; f < 4; ++f) {
            af[f]  = *(const bf16x8*)&As[offa[f]];
            bfr[f] = *(const bf16x8*)&Bs[offb[f]];
        }
#pragma unroll
        for (int mf = 0; mf < 4; ++mf)
#pragma unroll
            for (int nf = 0; nf < 4; ++nf)
                acc[mf][nf] = __builtin_amdgcn_mfma_f32_16x16x32_bf16(
                    af[mf], bfr[nf], acc[mf][nf], 0, 0, 0);
    }

    if (EPI == 0) {
#pragma unroll
        for (int nf = 0; nf < 4; ++nf) {
            const int n = n0 + wc * 64 + nf * 16 + lr;
            const float bj = bias[n];
#pragma unroll
            for (int mf = 0; mf < 4; ++mf)
#pragma unroll
                for (int r = 0; r < 4; ++r) {
                    const int m = m0 + wr * 64 + mf * 16 + lg * 4 + r;
                    C[(size_t)m * N + n] = acc[mf][nf][r] + bj;
                }
        }
    } else {
        const int tt = n0 >> 10;
        float bj[4]; int hh[4];
#pragma unroll
        for (int nf = 0; nf < 4; ++nf) {
            const int n = n0 + wc * 64 + nf * 16 + lr;
            bj[nf] = bias[n];
            hh[nf] = (n >> 6) & (NH - 1);
        }
#pragma unroll
        for (int mf = 0; mf < 4; ++mf)
#pragma unroll
            for (int r = 0; r < 4; ++r) {
                const int m = m0 + wr * 64 + mf * 16 + lg * 4 + r;
                const int b = m >> 11;
                const int s = m & (NS - 1);
                float v[4];
#pragma unroll
                for (int nf = 0; nf < 4; ++nf) v[nf] = acc[mf][nf][r] + bj[nf];
                if (tt < 2) {
#pragma unroll
                    for (int p = 0; p < 2; ++p) {
                        const int d = p * 16 + lr;
                        const float c  = cosT[s * ND + d];
                        const float sn = sinT[s * ND + d];
                        const float lo = v[p] * c - v[p + 2] * sn;
                        const float hi = v[p + 2] * c + v[p] * sn;
                        v[p] = lo; v[p + 2] = hi;
                    }
                    if (tt == 0) {
#pragma unroll
                        for (int nf = 0; nf < 4; ++nf) v[nf] *= KQPRE;
                    }
                }
#pragma unroll
                for (int nf = 0; nf < 4; ++nf)
                    Cb[((size_t)((tt * NB + b) * NH + hh[nf]) * NS + s) * ND
                       + nf * 16 + lr] = f2bf(v[nf]);
            }
    }
}

// ===========================================================================
// Swapped-operand bf16 MFMA flash attention — r13/r16-verbatim (verified)
// ===========================================================================
__global__ __launch_bounds__(256)
void attn_kernel(const ushort_t* __restrict__ qkvb, ushort_t* __restrict__ obuf)
{
    __shared__ ushort_t Ks[64 * 72];
    __shared__ ushort_t Vs[64 * 64];
    __shared__ ushort_t Ps[128 * 72];

    const int tid  = threadIdx.x;
    const int lane = tid & 63;
    const int wid  = tid >> 6;
    const int lr   = lane & 15;
    const int lg   = lane >> 4;

    const int orig = blockIdx.x;                 // 0..1023
    const int wg   = (orig & 7) * 128 + (orig >> 3);
    const int bh   = wg >> 4;
    const int b = bh >> 4, h = bh & (NH - 1);
    const int q0 = (wg & 15) * 128;

    const ushort_t* qbase = qkvb + ((size_t)((0 * NB + b) * NH + h)) * (NS * ND);
    const ushort_t* kbase = qkvb + ((size_t)((1 * NB + b) * NH + h)) * (NS * ND);
    const ushort_t* vbase = qkvb + ((size_t)((2 * NB + b) * NH + h)) * (NS * ND);

    bf16x8 onesf;
#pragma unroll
    for (int j = 0; j < 8; ++j) onesf[j] = (short)0x3F80;

    bf16x8 qf[2][2];
#pragma unroll
    for (int st = 0; st < 2; ++st)
#pragma unroll
        for (int kh = 0; kh < 2; ++kh)
            qf[st][kh] = *(const bf16x8*)(qbase + (size_t)(q0 + wid * 32 + st * 16 + lr) * ND
                                          + kh * 32 + lg * 8);

    const int sc = tid & 7;
    const int sr0 = tid >> 3;

    uint4 krg[2], vrg[2];
#pragma unroll
    for (int it = 0; it < 2; ++it) {
        const int r = sr0 + it * 32;
        krg[it] = *(const uint4*)(kbase + r * ND + sc * 8);
        vrg[it] = *(const uint4*)(vbase + r * ND + sc * 8);
    }

    f32x4 acc_o[2][4];
    f32x4 acc_l[2];
#pragma unroll
    for (int st = 0; st < 2; ++st) {
        acc_l[st] = (f32x4){0.f, 0.f, 0.f, 0.f};
#pragma unroll
        for (int dk = 0; dk < 4; ++dk) acc_o[st][dk] = (f32x4){0.f, 0.f, 0.f, 0.f};
    }

    for (int kt = 0; kt < NS; kt += KVB) {
        __syncthreads();
#pragma unroll
        for (int it = 0; it < 2; ++it) {
            const int r = sr0 + it * 32;
            *(uint4*)&Ks[r * 72 + sc * 8] = krg[it];
            union { uint4 v; ushort_t us[8]; } pu;
            pu.v = vrg[it];
#pragma unroll
            for (int j = 0; j < 8; ++j) {
                const int sw = (j ^ sc) << 4;
                Vs[(sc * 8 + j) * 64 + ((((r * 2) ^ sw)) >> 1)] = pu.us[j];
            }
        }
        __syncthreads();
        if (kt + KVB < NS) {
#pragma unroll
            for (int it = 0; it < 2; ++it) {
                const int r = kt + KVB + sr0 + it * 32;
                krg[it] = *(const uint4*)(kbase + (size_t)r * ND + sc * 8);
                vrg[it] = *(const uint4*)(vbase + (size_t)r * ND + sc * 8);
            }
        }

        f32x4 s[2][4];
#pragma unroll
        for (int st = 0; st < 2; ++st)
#pragma unroll
            for (int kvf = 0; kvf < 4; ++kvf) s[st][kvf] = (f32x4){0.f, 0.f, 0.f, 0.f};
        __builtin_amdgcn_s_setprio(1);
#pragma unroll
        for (int kh = 0; kh < 2; ++kh)
#pragma unroll
            for (int kvf = 0; kvf < 4; ++kvf) {
                const bf16x8 kf = *(const bf16x8*)&Ks[(kvf * 16 + lr) * 72 + kh * 32 + lg * 8];
                s[0][kvf] = __builtin_amdgcn_mfma_f32_16x16x32_bf16(kf, qf[0][kh], s[0][kvf], 0, 0, 0);
                s[1][kvf] = __builtin_amdgcn_mfma_f32_16x16x32_bf16(kf, qf[1][kh], s[1][kvf], 0, 0, 0);
            }
        __builtin_amdgcn_s_setprio(0);

#pragma unroll
        for (int st = 0; st < 2; ++st) {
            const int prow = (wid * 32 + st * 16 + lr) * 72;
#pragma unroll
            for (int kvf = 0; kvf < 4; ++kvf) {
                const float p0 = __builtin_amdgcn_exp2f(s[st][kvf][0]);
                const float p1 = __builtin_amdgcn_exp2f(s[st][kvf][1]);
                const float p2 = __builtin_amdgcn_exp2f(s[st][kvf][2]);
                const float p3 = __builtin_amdgcn_exp2f(s[st][kvf][3]);
                const unsigned w01 = pk_bf16(p0, p1);
                const unsigned w23 = pk_bf16(p2, p3);
                *(uint2*)&Ps[prow + kvf * 16 + lg * 4] = make_uint2(w01, w23);
            }
        }
        asm volatile("s_waitcnt lgkmcnt(0)" ::: "memory");
        __builtin_amdgcn_sched_barrier(0);

        __builtin_amdgcn_s_setprio(1);
#pragma unroll
        for (int kh = 0; kh < 2; ++kh) {
            const bf16x8 pf0 = *(const bf16x8*)&Ps[(wid * 32 + 0  + lr) * 72 + kh * 32 + lg * 8];
            const bf16x8 pf1 = *(const bf16x8*)&Ps[(wid * 32 + 16 + lr) * 72 + kh * 32 + lg * 8];
            acc_l[0] = __builtin_amdgcn_mfma_f32_16x16x32_bf16(pf0, onesf, acc_l[0], 0, 0, 0);
            acc_l[1] = __builtin_amdgcn_mfma_f32_16x16x32_bf16(pf1, onesf, acc_l[1], 0, 0, 0);
#pragma unroll
            for (int dk = 0; dk < 4; ++dk) {
                const int d = dk * 16 + lr;
                const int sw = ((d & 7) ^ ((d >> 3) & 7)) << 4;
                const bf16x8 vf = *(const bf16x8*)&Vs[d * 64 + (((kh * 64 + lg * 16) ^ sw) >> 1)];
                acc_o[0][dk] = __builtin_amdgcn_mfma_f32_16x16x32_bf16(pf0, vf, acc_o[0][dk], 0, 0, 0);
                acc_o[1][dk] = __builtin_amdgcn_mfma_f32_16x16x32_bf16(pf1, vf, acc_o[1][dk], 0, 0, 0);
            }
        }
        __builtin_amdgcn_s_setprio(0);
    }

#pragma unroll
    for (int st = 0; st < 2; ++st) {
        float invq[4];
#pragma unroll
        for (int reg = 0; reg < 4; ++reg)
            invq[reg] = 1.0f / acc_l[st][reg];
#pragma unroll
        for (int dk = 0; dk < 4; ++dk)
#pragma unroll
            for (int reg = 0; reg < 4; ++reg) {
                const int q = q0 + wid * 32 + st * 16 + lg * 4 + reg;
                const int d = dk * 16 + lr;
                obuf[((size_t)(b * NS + q)) * NE + h * ND + d] =
                    f2bf(acc_o[st][dk][reg] * invq[reg]);
            }
    }
}

// ===========================================================================
extern "C" void kernel_launch(void* const* d_in, const int* in_sizes, int n_in,
                              void* d_out, int out_size, void* d_ws, size_t ws_size,
                              hipStream_t stream)
{
    const float* x    = (const float*)d_in[0];
    const float* Win  = (const float*)d_in[1];
    const float* bin  = (const float*)d_in[2];
    const float* Wout = (const float*)d_in[3];
    const float* bout = (const float*)d_in[4];
    const float* cosT = (const float*)d_in[5];
    const float* sinT = (const float*)d_in[6];
    float* out  = (float*)d_out;

    ushort_t* qkvb  = (ushort_t*)d_ws;
    ushort_t* obufb = qkvb + (size_t)3 * NB * NH * NS * ND;
    ushort_t* xb    = obufb + (size_t)NB * NS * NE;
    ushort_t* Wib   = xb + (size_t)NB * NS * NE;
    ushort_t* Wob   = Wib + (size_t)3 * NE * NE;

    cvt3_f32_bf16<<<6144, 256, 0, stream>>>(x, xb, Win, Wib, Wout, Wob);

    // 1) QKV projection 256^2 counted-vmcnt pipeline + fused RoPE + q scale
    gemm1_256<<<384, 512, 0, stream>>>(xb, Wib, bin, qkvb, cosT, sinT);
    // 2) attention (r16-verbatim) -> bf16 obuf [B][S][E]
    attn_kernel<<<dim3(NB * NH * (NS / 128)), 256, 0, stream>>>(qkvb, obufb);
    // 3) output projection (m97 structure, verified)
    gemm_bf16<0><<<dim3(NE / 128, NB * NS / 128), 256, 0, stream>>>(
        obufb, Wob, bout, out, nullptr, nullptr, nullptr, NB * NS, NE, NE);
}

// Round 19
// 230.964 us; speedup vs baseline: 1.1813x; 1.0018x over previous
//
#include <hip/hip_runtime.h>

#define NB 4
#define NS 2048
#define NE 1024
#define NH 16
#define ND 64
#define KVB 64

typedef unsigned short ushort_t;
typedef __attribute__((ext_vector_type(8))) short bf16x8;
typedef __attribute__((ext_vector_type(4))) float f32x4;

#define KQPRE 0.18033688011112042f   // 0.125 * log2(e), folded into q at gemm1

static __device__ __forceinline__ ushort_t f2bf(float f) {
    union { float f; unsigned int u; } v; v.f = f;
    unsigned int r = v.u + 0x7FFF + ((v.u >> 16) & 1);   // RNE
    return (ushort_t)(r >> 16);
}
static __device__ __forceinline__ float bf2f(ushort_t b) {
    union { unsigned u; float f; } v; v.u = ((unsigned)b) << 16;
    return v.f;
}

static __device__ __forceinline__ unsigned pk_bf16(float lo, float hi) {
    unsigned r;
    asm("v_cvt_pk_bf16_f32 %0, %1, %2" : "=v"(r) : "v"(lo), "v"(hi));
    return r;
}

static __device__ __forceinline__ void gload16(const void* g, void* l) {
    __builtin_amdgcn_global_load_lds(
        (const __attribute__((address_space(1))) void*)g,
        (__attribute__((address_space(3))) void*)l,
        16, 0, 0);
}

// ===========================================================================
// fused fp32 -> bf16 bulk convert for x (4096 blks), Win (1536), Wout (512)
// ===========================================================================
__global__ __launch_bounds__(256)
void cvt3_f32_bf16(const float* __restrict__ x,  ushort_t* __restrict__ xb,
                   const float* __restrict__ Wi, ushort_t* __restrict__ Wib,
                   const float* __restrict__ Wo, ushort_t* __restrict__ Wob)
{
    const int blk = blockIdx.x;
    const float* src; ushort_t* dst; int i;
    if (blk < 4096)      { src = x;  dst = xb;  i = blk * 256 + threadIdx.x; }
    else if (blk < 5632) { src = Wi; dst = Wib; i = (blk - 4096) * 256 + threadIdx.x; }
    else                 { src = Wo; dst = Wob; i = (blk - 5632) * 256 + threadIdx.x; }
    const float4 a = ((const float4*)src)[i * 2];
    const float4 b = ((const float4*)src)[i * 2 + 1];
    union { ushort_t us[8]; uint4 v; } pk;
    pk.us[0] = f2bf(a.x); pk.us[1] = f2bf(a.y); pk.us[2] = f2bf(a.z); pk.us[3] = f2bf(a.w);
    pk.us[4] = f2bf(b.x); pk.us[5] = f2bf(b.y); pk.us[6] = f2bf(b.z); pk.us[7] = f2bf(b.w);
    ((uint4*)dst)[i] = pk.v;
}

// ===========================================================================
// gemm1_256 — verified r17: 256x256 counted-vmcnt pipeline (T3+T4) with
// fused RoPE + q pre-scale epilogue.
// ===========================================================================
__global__ __launch_bounds__(512, 2)
void gemm1_256(const ushort_t* __restrict__ A, const ushort_t* __restrict__ W,
               const float* __restrict__ bias, ushort_t* __restrict__ Cb,
               const float* __restrict__ cosT, const float* __restrict__ sinT)
{
    const int M = NB * NS, N = 3 * NE, K = NE;
    const int NK = K / 64;                    // 16 K-tiles
    __shared__ ushort_t As[2][256 * 64];
    __shared__ ushort_t Bs[2][256 * 64];

    const int tid  = threadIdx.x;
    const int lane = tid & 63;
    const int wid  = tid >> 6;                // 0..7
    const int lr   = lane & 15;
    const int lg   = lane >> 4;
    const int wr   = wid >> 2;                // 0..1 (M half)
    const int wc   = wid & 3;                 // 0..3 (N quarter)

    const int orig = blockIdx.x;
    const int wg   = (orig & 7) * 48 + (orig >> 3);
    const int bx   = wg % 12;
    const int by   = wg / 12;
    const int m0 = by * 256, n0 = bx * 256;
    (void)M;

    size_t srcA[4], srcB[4];
    int dstoff[4];
#pragma unroll
    for (int p = 0; p < 4; ++p) {
        const int g   = p * 512 + tid;
        const int row = g >> 3;
        const int cl  = (g & 7) ^ (row & 7);
        srcA[p] = (size_t)(m0 + row) * K + cl * 8;
        srcB[p] = (size_t)(n0 + row) * K + cl * 8;
        dstoff[p] = (p * 512 + wid * 64) * 8;
    }

    const int x7  = lr & 7;
    const int pc0 = ((0 + lg) ^ x7) * 8;
    const int pc1 = ((4 + lg) ^ x7) * 8;
    int offa[8], offb[4];
#pragma unroll
    for (int mf = 0; mf < 8; ++mf) offa[mf] = (wr * 128 + mf * 16 + lr) * 64;
#pragma unroll
    for (int nf = 0; nf < 4; ++nf) offb[nf] = (wc * 64 + nf * 16 + lr) * 64;

    f32x4 acc[8][4];
#pragma unroll
    for (int i = 0; i < 8; ++i)
#pragma unroll
        for (int j = 0; j < 4; ++j) acc[i][j] = (f32x4){0.f, 0.f, 0.f, 0.f};

#pragma unroll
    for (int p = 0; p < 4; ++p) {
        gload16(A + srcA[p], (ushort_t*)As[0] + dstoff[p]);
        gload16(W + srcB[p], (ushort_t*)Bs[0] + dstoff[p]);
    }
#pragma unroll
    for (int p = 0; p < 4; ++p) {
        gload16(A + srcA[p] + 64, (ushort_t*)As[1] + dstoff[p]);
        gload16(W + srcB[p] + 64, (ushort_t*)Bs[1] + dstoff[p]);
    }
    asm volatile("s_waitcnt vmcnt(8)" ::: "memory");
    __builtin_amdgcn_s_barrier();
    __builtin_amdgcn_sched_barrier(0);

    int cur = 0;
    for (int t = 0; t < NK; ++t) {
        bf16x8 af[8], bfv[4];
#pragma unroll
        for (int mf = 0; mf < 8; ++mf) af[mf] = *(const bf16x8*)&As[cur][offa[mf] + pc0];
#pragma unroll
        for (int nf = 0; nf < 4; ++nf) bfv[nf] = *(const bf16x8*)&Bs[cur][offb[nf] + pc0];
        __builtin_amdgcn_s_setprio(1);
#pragma unroll
        for (int mf = 0; mf < 8; ++mf)
#pragma unroll
            for (int nf = 0; nf < 4; ++nf)
                acc[mf][nf] = __builtin_amdgcn_mfma_f32_16x16x32_bf16(
                    af[mf], bfv[nf], acc[mf][nf], 0, 0, 0);
        __builtin_amdgcn_s_setprio(0);
#pragma unroll
        for (int mf = 0; mf < 8; ++mf) af[mf] = *(const bf16x8*)&As[cur][offa[mf] + pc1];
#pragma unroll
        for (int nf = 0; nf < 4; ++nf) bfv[nf] = *(const bf16x8*)&Bs[cur][offb[nf] + pc1];
        asm volatile("s_waitcnt lgkmcnt(0)" ::: "memory");
        __builtin_amdgcn_sched_barrier(0);
        __builtin_amdgcn_s_barrier();
        __builtin_amdgcn_sched_barrier(0);
        if (t + 2 < NK) {
            const int koff = (t + 2) * 64;
#pragma unroll
            for (int p = 0; p < 4; ++p) {
                gload16(A + srcA[p] + koff, (ushort_t*)As[cur] + dstoff[p]);
                gload16(W + srcB[p] + koff, (ushort_t*)Bs[cur] + dstoff[p]);
            }
        }
        __builtin_amdgcn_s_setprio(1);
#pragma unroll
        for (int mf = 0; mf < 8; ++mf)
#pragma unroll
            for (int nf = 0; nf < 4; ++nf)
                acc[mf][nf] = __builtin_amdgcn_mfma_f32_16x16x32_bf16(
                    af[mf], bfv[nf], acc[mf][nf], 0, 0, 0);
        __builtin_amdgcn_s_setprio(0);
        if (t + 1 < NK) {
            if (t + 2 < NK) asm volatile("s_waitcnt vmcnt(8)" ::: "memory");
            else            asm volatile("s_waitcnt vmcnt(0)" ::: "memory");
            __builtin_amdgcn_s_barrier();
            __builtin_amdgcn_sched_barrier(0);
        }
        cur ^= 1;
    }

    const int tt = n0 >> 10;
    const int nbase = n0 + wc * 64;
    const int h = (nbase >> 6) & (NH - 1);
    float bj[4];
#pragma unroll
    for (int nf = 0; nf < 4; ++nf) bj[nf] = bias[nbase + nf * 16 + lr];
#pragma unroll
    for (int mf = 0; mf < 8; ++mf)
#pragma unroll
        for (int r = 0; r < 4; ++r) {
            const int m = m0 + wr * 128 + mf * 16 + lg * 4 + r;
            const int b = m >> 11;
            const int s = m & (NS - 1);
            float v[4];
#pragma unroll
            for (int nf = 0; nf < 4; ++nf) v[nf] = acc[mf][nf][r] + bj[nf];
            if (tt < 2) {
#pragma unroll
                for (int p = 0; p < 2; ++p) {
                    const int d = p * 16 + lr;
                    const float c  = cosT[s * ND + d];
                    const float sn = sinT[s * ND + d];
                    const float lo = v[p] * c - v[p + 2] * sn;
                    const float hi = v[p + 2] * c + v[p] * sn;
                    v[p] = lo; v[p + 2] = hi;
                }
                if (tt == 0) {
#pragma unroll
                    for (int nf = 0; nf < 4; ++nf) v[nf] *= KQPRE;
                }
            }
#pragma unroll
            for (int nf = 0; nf < 4; ++nf)
                Cb[((size_t)((tt * NB + b) * NH + h) * NS + s) * ND
                   + nf * 16 + lr] = f2bf(v[nf]);
        }
}

// ===========================================================================
// bf16 MFMA GEMM (m97 structure) — verified; used for gemm2 (EPI=0).
// ===========================================================================
template<int EPI>
__global__ __launch_bounds__(256)
void gemm_bf16(const ushort_t* __restrict__ A, const ushort_t* __restrict__ W,
               const float* __restrict__ bias, float* __restrict__ C,
               ushort_t* __restrict__ Cb, const float* __restrict__ cosT,
               const float* __restrict__ sinT, int M, int N, int K)
{
    __shared__ ushort_t As[128 * 32];
    __shared__ ushort_t Bs[128 * 32];
    const int tid  = threadIdx.x;
    const int lane = tid & 63;
    const int wid  = tid >> 6;
    const int lr   = lane & 15;
    const int lg   = lane >> 4;

    const int lin   = blockIdx.y * gridDim.x + blockIdx.x;
    const int chunk = (gridDim.x * gridDim.y) >> 3;
    const int lin2  = (lin & 7) * chunk + (lin >> 3);
    const int bx    = lin2 % gridDim.x;
    const int by    = lin2 / gridDim.x;
    const int m0 = by * 128;
    const int n0 = bx * 128;
    const int wr = wid >> 1, wc = wid & 1;

    size_t srcoff[2];
    int ldsoff[2];
#pragma unroll
    for (int p = 0; p < 2; ++p) {
        const int chnk = p * 256 + tid;
        const int row = chnk >> 2;
        const int sp  = chnk & 3;
        const int c   = sp ^ ((row >> 1) & 3);
        srcoff[p] = (size_t)row * K + c * 8;
        ldsoff[p] = (p * 256 + wid * 64) * 8;
    }
    const ushort_t* Ag = A + (size_t)m0 * K;
    const ushort_t* Wg = W + (size_t)n0 * K;

    int offa[4], offb[4];
#pragma unroll
    for (int f = 0; f < 4; ++f) {
        const int ra = wr * 64 + f * 16 + lr;
        offa[f] = ra * 32 + (lg ^ ((ra >> 1) & 3)) * 8;
        const int rb = wc * 64 + f * 16 + lr;
        offb[f] = rb * 32 + (lg ^ ((rb >> 1) & 3)) * 8;
    }

    f32x4 acc[4][4];
#pragma unroll
    for (int i = 0; i < 4; ++i)
#pragma unroll
        for (int j = 0; j < 4; ++j) acc[i][j] = (f32x4){0.f, 0.f, 0.f, 0.f};

    for (int k0 = 0; k0 < K; k0 += 32) {
        __syncthreads();
#pragma unroll
        for (int p = 0; p < 2; ++p) {
            gload16(Ag + srcoff[p] + k0, (ushort_t*)As + ldsoff[p]);
            gload16(Wg + srcoff[p] + k0, (ushort_t*)Bs + ldsoff[p]);
        }
        __syncthreads();
        bf16x8 af[4], bfr[4];
#pragma unroll
        for (int f = 0; f < 4; ++f) {
            af[f]  = *(const bf16x8*)&As[offa[f]];
            bfr[f] = *(const bf16x8*)&Bs[offb[f]];
        }
#pragma unroll
        for (int mf = 0; mf < 4; ++mf)
#pragma unroll
            for (int nf = 0; nf < 4; ++nf)
                acc[mf][nf] = __builtin_amdgcn_mfma_f32_16x16x32_bf16(
                    af[mf], bfr[nf], acc[mf][nf], 0, 0, 0);
    }

    if (EPI == 0) {
#pragma unroll
        for (int nf = 0; nf < 4; ++nf) {
            const int n = n0 + wc * 64 + nf * 16 + lr;
            const float bj = bias[n];
#pragma unroll
            for (int mf = 0; mf < 4; ++mf)
#pragma unroll
                for (int r = 0; r < 4; ++r) {
                    const int m = m0 + wr * 64 + mf * 16 + lg * 4 + r;
                    C[(size_t)m * N + n] = acc[mf][nf][r] + bj;
                }
        }
    } else {
        const int tt = n0 >> 10;
        float bj[4]; int hh[4];
#pragma unroll
        for (int nf = 0; nf < 4; ++nf) {
            const int n = n0 + wc * 64 + nf * 16 + lr;
            bj[nf] = bias[n];
            hh[nf] = (n >> 6) & (NH - 1);
        }
#pragma unroll
        for (int mf = 0; mf < 4; ++mf)
#pragma unroll
            for (int r = 0; r < 4; ++r) {
                const int m = m0 + wr * 64 + mf * 16 + lg * 4 + r;
                const int b = m >> 11;
                const int s = m & (NS - 1);
                float v[4];
#pragma unroll
                for (int nf = 0; nf < 4; ++nf) v[nf] = acc[mf][nf][r] + bj[nf];
                if (tt < 2) {
#pragma unroll
                    for (int p = 0; p < 2; ++p) {
                        const int d = p * 16 + lr;
                        const float c  = cosT[s * ND + d];
                        const float sn = sinT[s * ND + d];
                        const float lo = v[p] * c - v[p + 2] * sn;
                        const float hi = v[p + 2] * c + v[p] * sn;
                        v[p] = lo; v[p + 2] = hi;
                    }
                    if (tt == 0) {
#pragma unroll
                        for (int nf = 0; nf < 4; ++nf) v[nf] *= KQPRE;
                    }
                }
#pragma unroll
                for (int nf = 0; nf < 4; ++nf)
                    Cb[((size_t)((tt * NB + b) * NH + hh[nf]) * NS + s) * ND
                       + nf * 16 + lr] = f2bf(v[nf]);
            }
    }
}

// ===========================================================================
// Swapped-operand bf16 MFMA flash attention — r13/r16/r17-verbatim (verified):
// packed-P LDS path, ones-MFMA rowsum, exp2 softmax (scale pre-folded),
// B3-as-fence, T1 XCD swizzle, T5 setprio, T14 prefetch.
// ===========================================================================
__global__ __launch_bounds__(256)
void attn_kernel(const ushort_t* __restrict__ qkvb, ushort_t* __restrict__ obuf)
{
    __shared__ ushort_t Ks[64 * 72];
    __shared__ ushort_t Vs[64 * 64];
    __shared__ ushort_t Ps[128 * 72];

    const int tid  = threadIdx.x;
    const int lane = tid & 63;
    const int wid  = tid >> 6;
    const int lr   = lane & 15;
    const int lg   = lane >> 4;

    const int orig = blockIdx.x;                 // 0..1023
    const int wg   = (orig & 7) * 128 + (orig >> 3);
    const int bh   = wg >> 4;
    const int b = bh >> 4, h = bh & (NH - 1);
    const int q0 = (wg & 15) * 128;

    const ushort_t* qbase = qkvb + ((size_t)((0 * NB + b) * NH + h)) * (NS * ND);
    const ushort_t* kbase = qkvb + ((size_t)((1 * NB + b) * NH + h)) * (NS * ND);
    const ushort_t* vbase = qkvb + ((size_t)((2 * NB + b) * NH + h)) * (NS * ND);

    bf16x8 onesf;
#pragma unroll
    for (int j = 0; j < 8; ++j) onesf[j] = (short)0x3F80;

    bf16x8 qf[2][2];
#pragma unroll
    for (int st = 0; st < 2; ++st)
#pragma unroll
        for (int kh = 0; kh < 2; ++kh)
            qf[st][kh] = *(const bf16x8*)(qbase + (size_t)(q0 + wid * 32 + st * 16 + lr) * ND
                                          + kh * 32 + lg * 8);

    const int sc = tid & 7;
    const int sr0 = tid >> 3;

    uint4 krg[2], vrg[2];
#pragma unroll
    for (int it = 0; it < 2; ++it) {
        const int r = sr0 + it * 32;
        krg[it] = *(const uint4*)(kbase + r * ND + sc * 8);
        vrg[it] = *(const uint4*)(vbase + r * ND + sc * 8);
    }

    f32x4 acc_o[2][4];
    f32x4 acc_l[2];
#pragma unroll
    for (int st = 0; st < 2; ++st) {
        acc_l[st] = (f32x4){0.f, 0.f, 0.f, 0.f};
#pragma unroll
        for (int dk = 0; dk < 4; ++dk) acc_o[st][dk] = (f32x4){0.f, 0.f, 0.f, 0.f};
    }

    for (int kt = 0; kt < NS; kt += KVB) {
        __syncthreads();                         // B1: prev tile reads done
#pragma unroll
        for (int it = 0; it < 2; ++it) {
            const int r = sr0 + it * 32;
            *(uint4*)&Ks[r * 72 + sc * 8] = krg[it];
            union { uint4 v; ushort_t us[8]; } pu;
            pu.v = vrg[it];
#pragma unroll
            for (int j = 0; j < 8; ++j) {
                const int sw = (j ^ sc) << 4;
                Vs[(sc * 8 + j) * 64 + ((((r * 2) ^ sw)) >> 1)] = pu.us[j];
            }
        }
        __syncthreads();                         // B2: staging visible
        if (kt + KVB < NS) {
#pragma unroll
            for (int it = 0; it < 2; ++it) {
                const int r = kt + KVB + sr0 + it * 32;
                krg[it] = *(const uint4*)(kbase + (size_t)r * ND + sc * 8);
                vrg[it] = *(const uint4*)(vbase + (size_t)r * ND + sc * 8);
            }
        }

        f32x4 s[2][4];
#pragma unroll
        for (int st = 0; st < 2; ++st)
#pragma unroll
            for (int kvf = 0; kvf < 4; ++kvf) s[st][kvf] = (f32x4){0.f, 0.f, 0.f, 0.f};
        __builtin_amdgcn_s_setprio(1);
#pragma unroll
        for (int kh = 0; kh < 2; ++kh)
#pragma unroll
            for (int kvf = 0; kvf < 4; ++kvf) {
                const bf16x8 kf = *(const bf16x8*)&Ks[(kvf * 16 + lr) * 72 + kh * 32 + lg * 8];
                s[0][kvf] = __builtin_amdgcn_mfma_f32_16x16x32_bf16(kf, qf[0][kh], s[0][kvf], 0, 0, 0);
                s[1][kvf] = __builtin_amdgcn_mfma_f32_16x16x32_bf16(kf, qf[1][kh], s[1][kvf], 0, 0, 0);
            }
        __builtin_amdgcn_s_setprio(0);

#pragma unroll
        for (int st = 0; st < 2; ++st) {
            const int prow = (wid * 32 + st * 16 + lr) * 72;
#pragma unroll
            for (int kvf = 0; kvf < 4; ++kvf) {
                const float p0 = __builtin_amdgcn_exp2f(s[st][kvf][0]);
                const float p1 = __builtin_amdgcn_exp2f(s[st][kvf][1]);
                const float p2 = __builtin_amdgcn_exp2f(s[st][kvf][2]);
                const float p3 = __builtin_amdgcn_exp2f(s[st][kvf][3]);
                const unsigned w01 = pk_bf16(p0, p1);
                const unsigned w23 = pk_bf16(p2, p3);
                *(uint2*)&Ps[prow + kvf * 16 + lg * 4] = make_uint2(w01, w23);
            }
        }
        asm volatile("s_waitcnt lgkmcnt(0)" ::: "memory");
        __builtin_amdgcn_sched_barrier(0);

        __builtin_amdgcn_s_setprio(1);
#pragma unroll
        for (int kh = 0; kh < 2; ++kh) {
            const bf16x8 pf0 = *(const bf16x8*)&Ps[(wid * 32 + 0  + lr) * 72 + kh * 32 + lg * 8];
            const bf16x8 pf1 = *(const bf16x8*)&Ps[(wid * 32 + 16 + lr) * 72 + kh * 32 + lg * 8];
            acc_l[0] = __builtin_amdgcn_mfma_f32_16x16x32_bf16(pf0, onesf, acc_l[0], 0, 0, 0);
            acc_l[1] = __builtin_amdgcn_mfma_f32_16x16x32_bf16(pf1, onesf, acc_l[1], 0, 0, 0);
#pragma unroll
            for (int dk = 0; dk < 4; ++dk) {
                const int d = dk * 16 + lr;
                const int sw = ((d & 7) ^ ((d >> 3) & 7)) << 4;
                const bf16x8 vf = *(const bf16x8*)&Vs[d * 64 + (((kh * 64 + lg * 16) ^ sw) >> 1)];
                acc_o[0][dk] = __builtin_amdgcn_mfma_f32_16x16x32_bf16(pf0, vf, acc_o[0][dk], 0, 0, 0);
                acc_o[1][dk] = __builtin_amdgcn_mfma_f32_16x16x32_bf16(pf1, vf, acc_o[1][dk], 0, 0, 0);
            }
        }
        __builtin_amdgcn_s_setprio(0);
    }

#pragma unroll
    for (int st = 0; st < 2; ++st) {
        float invq[4];
#pragma unroll
        for (int reg = 0; reg < 4; ++reg)
            invq[reg] = 1.0f / acc_l[st][reg];
#pragma unroll
        for (int dk = 0; dk < 4; ++dk)
#pragma unroll
            for (int reg = 0; reg < 4; ++reg) {
                const int q = q0 + wid * 32 + st * 16 + lg * 4 + reg;
                const int d = dk * 16 + lr;
                obuf[((size_t)(b * NS + q)) * NE + h * ND + d] =
                    f2bf(acc_o[st][dk][reg] * invq[reg]);
            }
    }
}

// ===========================================================================
extern "C" void kernel_launch(void* const* d_in, const int* in_sizes, int n_in,
                              void* d_out, int out_size, void* d_ws, size_t ws_size,
                              hipStream_t stream)
{
    const float* x    = (const float*)d_in[0];
    const float* Win  = (const float*)d_in[1];
    const float* bin  = (const float*)d_in[2];
    const float* Wout = (const float*)d_in[3];
    const float* bout = (const float*)d_in[4];
    const float* cosT = (const float*)d_in[5];
    const float* sinT = (const float*)d_in[6];
    float* out  = (float*)d_out;

    ushort_t* qkvb  = (ushort_t*)d_ws;
    ushort_t* obufb = qkvb + (size_t)3 * NB * NH * NS * ND;
    ushort_t* xb    = obufb + (size_t)NB * NS * NE;
    ushort_t* Wib   = xb + (size_t)NB * NS * NE;
    ushort_t* Wob   = Wib + (size_t)3 * NE * NE;

    cvt3_f32_bf16<<<6144, 256, 0, stream>>>(x, xb, Win, Wib, Wout, Wob);

    // 1) QKV projection (256^2 counted-vmcnt pipeline) + fused RoPE + q scale
    gemm1_256<<<384, 512, 0, stream>>>(xb, Wib, bin, qkvb, cosT, sinT);
    // 2) attention (verified) -> bf16 obuf [B][S][E]
    attn_kernel<<<dim3(NB * NH * (NS / 128)), 256, 0, stream>>>(qkvb, obufb);
    // 3) output projection (m97 structure, verified)
    gemm_bf16<0><<<dim3(NE / 128, NB * NS / 128), 256, 0, stream>>>(
        obufb, Wob, bout, out, nullptr, nullptr, nullptr, NB * NS, NE, NE);
}